// Round 9
// baseline (354.620 us; speedup 1.0000x reference)
//
#include <hip/hip_runtime.h>

#define S_LEN 2048
#define DMODEL 4096
#define NH 32
#define NKV 8
#define DH 128
#define QDIM (NH*DH)      // 4096
#define NQKV 6144         // fused projection width
#define SCALE 0.08838834764831845f

typedef __attribute__((ext_vector_type(8))) short short8;
typedef __attribute__((ext_vector_type(4))) float f32x4;
typedef __attribute__((ext_vector_type(4))) unsigned short us4;

__device__ __forceinline__ unsigned short f2bf(float f) {
  union { float f; unsigned int u; } v; v.f = f;
  unsigned int r = v.u + 0x7FFFu + ((v.u >> 16) & 1u);
  return (unsigned short)(r >> 16);
}
__device__ __forceinline__ float bf2f(unsigned short h) {
  union { unsigned int u; float f; } v; v.u = ((unsigned int)h) << 16;
  return v.f;
}
__device__ __forceinline__ short8 pack_bf16x8(float4 a, float4 b) {
  unsigned int u0, u1, u2, u3;
  asm("v_cvt_pk_bf16_f32 %0, %1, %2" : "=v"(u0) : "v"(a.x), "v"(a.y));
  asm("v_cvt_pk_bf16_f32 %0, %1, %2" : "=v"(u1) : "v"(a.z), "v"(a.w));
  asm("v_cvt_pk_bf16_f32 %0, %1, %2" : "=v"(u2) : "v"(b.x), "v"(b.y));
  asm("v_cvt_pk_bf16_f32 %0, %1, %2" : "=v"(u3) : "v"(b.z), "v"(b.w));
  union { unsigned int u[4]; short8 s; } r;
  r.u[0] = u0; r.u[1] = u1; r.u[2] = u2; r.u[3] = u3;
  return r.s;
}

// ---------------- f32 -> bf16 convert (x only; weights converted in-GEMM) ----------------
__global__ __launch_bounds__(256) void cvt_x(const float* __restrict__ in,
                                             unsigned short* __restrict__ out) {
  int i = blockIdx.x * 256 + threadIdx.x;
  const float4 f = reinterpret_cast<const float4*>(in)[i];
  us4 o;
  o.x = f2bf(f.x); o.y = f2bf(f.y); o.z = f2bf(f.z); o.w = f2bf(f.w);
  reinterpret_cast<us4*>(out)[i] = o;
}

// ---------------- (BM x BN) 8-phase GEMM, B staged directly from f32 ----------------
// C[M,N] = A[M,K](bf16) * B[N,K]^T(f32, up to 3 concatenated row-blocks split at R1/R2).
// 512 thr = 8 waves (2M x 4N). BK=64. Per K-tile:
//   ph1{af-lo+bf-lo ds_reads; ISSUE B-f32 loads(t+2); bar; MFMA; bar}
//   ph2{af-hi+bf-hi ds_reads; bar; MFMA; bar}            [all buf-c reads done]
//   ph3{vmcnt(0) (drains A(t+1) glds + B(t+2) regs); cvt+ds_write B(t+2)->buf c; MFMA; bar}
//   ph4{STAGE_A(t+2) via global_load_lds; MFMA; lgkmcnt(0); bar}
// LDS rows XOR-swizzled by ((row&7)<<4) on write-source and read sides.
template<int M_, int N_, int K_, int BM_, int BN_, int OUT_BF16, int CHN, int R1, int R2>
__global__ __launch_bounds__(512) void gemm8p(const unsigned short* __restrict__ A,
                                              const float* __restrict__ B0,
                                              const float* __restrict__ B1,
                                              const float* __restrict__ B2,
                                              void* __restrict__ Cv) {
  constexpr int ATILE = BM_ * 128;
  constexpr int BTILE = BN_ * 128;
  constexpr int BUF = ATILE + BTILE;
  constexpr int LPA = BM_ / 64;          // A gload_lds per thread
  constexpr int LPB = BN_ / 64;          // B 16B-slots per thread
  constexpr int MI = BM_ / 32, NF = BN_ / 64;
  constexpr int MIL = MI / 2, NFL = NF / 2;
  constexpr int NT = K_ / 64;
  __shared__ char lds[2 * BUF];

  const int tid = threadIdx.x;
  const int lane = tid & 63, wave = tid >> 6;
  const int wm = wave >> 2, wn = wave & 3;
  const int fr = lane & 15, fq = lane >> 4;

  const int lin = blockIdx.x;
  const int xcd = lin & 7;
  const int slot = lin >> 3;
  const long n0 = (long)(xcd * CHN + slot % CHN) * BN_;
  const long m0 = (long)(slot / CHN) * BM_;

  // per-slot B f32 source pointers (swizzle folded into the global column)
  const char* pB[LPB];
  int bslot[LPB];
#pragma unroll
  for (int u = 0; u < LPB; ++u) {
    int b = u * 8192 + tid * 16;
    int row = b >> 7;
    int colx = (b & 127) ^ ((row & 7) << 4);
    long n = n0 + row;
    const float* base = (n < R1) ? B0 + n * (long)K_
                      : (n < R2) ? B1 + (n - R1) * (long)K_
                                 : B2 + (n - (long)R2) * (long)K_;
    pB[u] = (const char*)base + (long)colx * 2;
    bslot[u] = b;
  }
  float4 breg[LPB][2];

  auto B_ISSUE = [&](int t) {
#pragma unroll
    for (int u = 0; u < LPB; ++u) {
      breg[u][0] = *reinterpret_cast<const float4*>(pB[u] + (long)t * 256);
      breg[u][1] = *reinterpret_cast<const float4*>(pB[u] + (long)t * 256 + 16);
    }
  };
  auto B_WRITE = [&](int c) {
#pragma unroll
    for (int u = 0; u < LPB; ++u)
      *reinterpret_cast<short8*>(lds + c * BUF + ATILE + bslot[u]) =
          pack_bf16x8(breg[u][0], breg[u][1]);
  };
  auto STAGE_A = [&](int t, int c) {
#pragma unroll
    for (int u = 0; u < LPA; ++u) {
      int b = u * 8192 + tid * 16;
      int row = b >> 7;
      int off = (b & 127) ^ ((row & 7) << 4);
      __builtin_amdgcn_global_load_lds(
        (const __attribute__((address_space(1))) void*)((const char*)A + ((m0 + row) * (long)K_ + t * 64) * 2 + off),
        (__attribute__((address_space(3))) void*)(lds + c * BUF + b), 16, 0, 0);
    }
  };

  f32x4 acc[MI][NF] = {};
  short8 af[MI][2];
  short8 bf[NF][2];

  // prologue: tiles 0 and 1 fully staged, drained
  B_ISSUE(0); B_WRITE(0); STAGE_A(0, 0);
  B_ISSUE(1); B_WRITE(1); STAGE_A(1, 1);
  asm volatile("s_waitcnt vmcnt(0)" ::: "memory");
  asm volatile("s_waitcnt lgkmcnt(0)" ::: "memory");
  __builtin_amdgcn_s_barrier();

  for (int t = 0; t < NT; ++t) {
    const int c = t & 1;
    const char* tb = lds + c * BUF;

    // ---- ph1: read af-lo, bf-lo; issue B-f32(t+2); MFMA lo x lo ----
#pragma unroll
    for (int mi = 0; mi < MIL; ++mi) {
      int row = wm * (BM_ / 2) + mi * 16 + fr;
#pragma unroll
      for (int ks = 0; ks < 2; ++ks)
        af[mi][ks] = *(const short8*)(tb + row * 128 + ((ks * 64 + fq * 16) ^ ((row & 7) << 4)));
    }
#pragma unroll
    for (int ni = 0; ni < NFL; ++ni) {
      int row = wn * (BN_ / 4) + ni * 16 + fr;
#pragma unroll
      for (int ks = 0; ks < 2; ++ks)
        bf[ni][ks] = *(const short8*)(tb + ATILE + row * 128 + ((ks * 64 + fq * 16) ^ ((row & 7) << 4)));
    }
    if (t + 2 < NT) B_ISSUE(t + 2);
    __builtin_amdgcn_sched_barrier(0);
    __builtin_amdgcn_s_barrier();
    __builtin_amdgcn_s_setprio(1);
#pragma unroll
    for (int mi = 0; mi < MIL; ++mi)
#pragma unroll
      for (int ni = 0; ni < NFL; ++ni)
#pragma unroll
        for (int ks = 0; ks < 2; ++ks)
          acc[mi][ni] = __builtin_amdgcn_mfma_f32_16x16x32_bf16(af[mi][ks], bf[ni][ks], acc[mi][ni], 0, 0, 0);
    __builtin_amdgcn_s_setprio(0);
    __builtin_amdgcn_s_barrier();

    // ---- ph2: read af-hi, bf-hi; MFMA lo x hi ----
#pragma unroll
    for (int mi = MIL; mi < MI; ++mi) {
      int row = wm * (BM_ / 2) + mi * 16 + fr;
#pragma unroll
      for (int ks = 0; ks < 2; ++ks)
        af[mi][ks] = *(const short8*)(tb + row * 128 + ((ks * 64 + fq * 16) ^ ((row & 7) << 4)));
    }
#pragma unroll
    for (int ni = NFL; ni < NF; ++ni) {
      int row = wn * (BN_ / 4) + ni * 16 + fr;
#pragma unroll
      for (int ks = 0; ks < 2; ++ks)
        bf[ni][ks] = *(const short8*)(tb + ATILE + row * 128 + ((ks * 64 + fq * 16) ^ ((row & 7) << 4)));
    }
    __builtin_amdgcn_s_barrier();
    __builtin_amdgcn_s_setprio(1);
#pragma unroll
    for (int mi = 0; mi < MIL; ++mi)
#pragma unroll
      for (int ni = NFL; ni < NF; ++ni)
#pragma unroll
        for (int ks = 0; ks < 2; ++ks)
          acc[mi][ni] = __builtin_amdgcn_mfma_f32_16x16x32_bf16(af[mi][ks], bf[ni][ks], acc[mi][ni], 0, 0, 0);
    __builtin_amdgcn_s_setprio(0);
    __builtin_amdgcn_s_barrier();

    // ---- ph3: drain loads; convert+write B(t+2) into buf c; MFMA hi x lo ----
    asm volatile("s_waitcnt vmcnt(0)" ::: "memory");
    if (t + 2 < NT) B_WRITE(c);
    __builtin_amdgcn_s_setprio(1);
#pragma unroll
    for (int mi = MIL; mi < MI; ++mi)
#pragma unroll
      for (int ni = 0; ni < NFL; ++ni)
#pragma unroll
        for (int ks = 0; ks < 2; ++ks)
          acc[mi][ni] = __builtin_amdgcn_mfma_f32_16x16x32_bf16(af[mi][ks], bf[ni][ks], acc[mi][ni], 0, 0, 0);
    __builtin_amdgcn_s_setprio(0);
    __builtin_amdgcn_s_barrier();

    // ---- ph4: stage A(t+2) via gload_lds; MFMA hi x hi; flush LDS writes ----
    if (t + 2 < NT) STAGE_A(t + 2, c);
    __builtin_amdgcn_s_setprio(1);
#pragma unroll
    for (int mi = MIL; mi < MI; ++mi)
#pragma unroll
      for (int ni = NFL; ni < NF; ++ni)
#pragma unroll
        for (int ks = 0; ks < 2; ++ks)
          acc[mi][ni] = __builtin_amdgcn_mfma_f32_16x16x32_bf16(af[mi][ks], bf[ni][ks], acc[mi][ni], 0, 0, 0);
    __builtin_amdgcn_s_setprio(0);
    asm volatile("s_waitcnt lgkmcnt(0)" ::: "memory");
    __builtin_amdgcn_s_barrier();
  }

  // epilogue
#pragma unroll
  for (int mi = 0; mi < MI; ++mi)
#pragma unroll
    for (int ni = 0; ni < NF; ++ni)
#pragma unroll
      for (int j = 0; j < 4; ++j) {
        long r = m0 + wm * (BM_ / 2) + mi * 16 + fq * 4 + j;
        long cc = n0 + wn * (BN_ / 4) + ni * 16 + fr;
        float v = acc[mi][ni][j];
        if (OUT_BF16) ((unsigned short*)Cv)[r * N_ + cc] = f2bf(v);
        else          ((float*)Cv)[r * N_ + cc] = v;
      }
}

// ---------------- YaRN RoPE in-place on fused QKV buffer (stride 6144) ----------------
__global__ __launch_bounds__(256) void rope_fused(unsigned short* __restrict__ C,
                                                  const float* __restrict__ cosb,
                                                  const float* __restrict__ sinb) {
  int idx = blockIdx.x * 256 + threadIdx.x;
  int i = idx & 63;
  int t = idx >> 6;       // s*40 + hh
  int hh = t % 40;
  int s = t / 40;
  const bool isQ = hh < 32;
  unsigned short* row = C + (size_t)s * NQKV + (isQ ? hh * DH : 4096 + (hh - 32) * DH);
  float sc = isQ ? SCALE : 1.0f;
  float c  = cosb[s * DH + i];
  float sn = sinb[s * DH + i];
  float x1 = bf2f(row[i]);
  float x2 = bf2f(row[i + 64]);
  row[i]      = f2bf((x1 * c - x2 * sn) * sc);
  row[i + 64] = f2bf((x2 * c + x1 * sn) * sc);
}

// ---------------- V transpose: C[s][5120+e] -> VT[kvh][d][s] ----------------
__global__ __launch_bounds__(256) void transpose_v(const unsigned short* __restrict__ Vbuf,
                                                   unsigned short* __restrict__ VT) {
  __shared__ unsigned short t[64][72];
  const int s0 = blockIdx.x * 64, e0 = blockIdx.y * 64;
  const int r = threadIdx.x >> 3, c = (threadIdx.x & 7) * 8;
#pragma unroll
  for (int half = 0; half < 2; ++half) {
    int row = r + half * 32;
    *reinterpret_cast<short8*>(&t[row][c]) =
        *reinterpret_cast<const short8*>(Vbuf + (size_t)(s0 + row) * NQKV + e0 + c);
  }
  __syncthreads();
  const int hh = e0 >> 7, dbase = e0 & 127;
#pragma unroll
  for (int half = 0; half < 2; ++half) {
    int row = r + half * 32;
    short8 o;
#pragma unroll
    for (int j = 0; j < 8; ++j) ((unsigned short*)&o)[j] = t[c + j][row];
    *reinterpret_cast<short8*>(VT + (size_t)hh * (DH * (size_t)S_LEN)
                               + (size_t)(dbase + row) * S_LEN + s0 + c) = o;
  }
}

// ---------------- GQA causal flash attention (round-6, unchanged) ----------------
__global__ __launch_bounds__(256) void attn_fwd(const unsigned short* __restrict__ C,
                                                const unsigned short* __restrict__ VT,
                                                unsigned short* __restrict__ Ob) {
  __shared__ unsigned short KVs[2][8192];   // 16 KB per buffer: K[32][128] swz @0, V^T[128][32] swz @8KB
  __shared__ unsigned short Pl[4][16 * 40];
  const int tid = threadIdx.x, lane = tid & 63, wave = tid >> 6;
  const int kvh = blockIdx.x & 7;
  const int p = blockIdx.x >> 3;
  const int h = kvh * 4 + wave;
  const int fr = lane & 15, fq = lane >> 4;
  const int q0s[2] = { p * 16, (127 - p) * 16 };
  const int tilesA = (p * 16 + 47) >> 5;
  const int tilesB = ((127 - p) * 16 + 47) >> 5;

  const unsigned short* Qbase = C + (size_t)h * DH;
  const unsigned short* Kbase = C + 4096 + (size_t)kvh * DH;
  const unsigned short* Vbase = VT + (size_t)kvh * (DH * (size_t)S_LEN);

  short8 qf[2][4];
#pragma unroll
  for (int s = 0; s < 2; ++s)
#pragma unroll
    for (int dc = 0; dc < 4; ++dc)
      qf[s][dc] = *reinterpret_cast<const short8*>(
          Qbase + (size_t)(q0s[s] + fr) * NQKV + dc * 32 + fq * 8);

  f32x4 o_acc[2][8] = {};
  float mrow[2][4] = {{-1e30f,-1e30f,-1e30f,-1e30f},{-1e30f,-1e30f,-1e30f,-1e30f}};
  float lpart[2][4] = {};

  auto STAGE = [&](int t, int buf) {
    const int kv0 = t * 32;
    char* dst = (char*)&KVs[buf][0];
#pragma unroll
    for (int sh = 0; sh < 2; ++sh) {
      int b = sh * 4096 + tid * 16;
      int krow = b >> 8;
      int kcol = (b & 255) ^ ((krow & 7) << 4);
      __builtin_amdgcn_global_load_lds(
          (const __attribute__((address_space(1))) void*)(Kbase + (size_t)(kv0 + krow) * NQKV + (kcol >> 1)),
          (__attribute__((address_space(3))) void*)(dst + b), 16, 0, 0);
      int vrow = b >> 6;
      int vcol = (b & 63) ^ ((((vrow ^ (vrow >> 2)) & 3)) << 4);
      __builtin_amdgcn_global_load_lds(
          (const __attribute__((address_space(1))) void*)(Vbase + (size_t)vrow * S_LEN + kv0 + (vcol >> 1)),
          (__attribute__((address_space(3))) void*)(dst + 8192 + b), 16, 0, 0);
    }
  };

  int cur = 0;
  STAGE(0, 0);
  asm volatile("s_waitcnt vmcnt(0)" ::: "memory");
  __syncthreads();

  for (int t = 0; t < tilesB; ++t) {
    const int kv0 = t * 32;
    if (t + 1 < tilesB) STAGE(t + 1, cur ^ 1);
    const char* kvb = (const char*)&KVs[cur][0];

#pragma unroll
    for (int s = 0; s < 2; ++s) {
      if (s == 0 && t >= tilesA) continue;
      const int q0 = q0s[s];

      f32x4 sacc[2] = {};
#pragma unroll
      for (int nt = 0; nt < 2; ++nt) {
        const int row = nt * 16 + fr;
#pragma unroll
        for (int dc = 0; dc < 4; ++dc) {
          short8 kf = *reinterpret_cast<const short8*>(
              kvb + row * 256 + ((dc * 64 + fq * 16) ^ ((row & 7) << 4)));
          sacc[nt] = __builtin_amdgcn_mfma_f32_16x16x32_bf16(qf[s][dc], kf, sacc[nt], 0, 0, 0);
        }
      }

      const bool needMask = (kv0 + 32 > q0);
      if (needMask) {
#pragma unroll
        for (int j = 0; j < 4; ++j) {
          int qrow = q0 + fq * 4 + j;
#pragma unroll
          for (int nt = 0; nt < 2; ++nt)
            sacc[nt][j] = ((kv0 + nt*16 + fr) <= qrow) ? sacc[nt][j] : -1e30f;
        }
      }
      bool ok = true;
      float lm[4];
#pragma unroll
      for (int j = 0; j < 4; ++j) {
        lm[j] = fmaxf(sacc[0][j], sacc[1][j]);
        ok = ok && (lm[j] <= mrow[s][j] + 8.f);
      }
      if (!__all(ok)) {
#pragma unroll
        for (int j = 0; j < 4; ++j) {
          float rm = lm[j];
          rm = fmaxf(rm, __shfl_xor(rm, 1));
          rm = fmaxf(rm, __shfl_xor(rm, 2));
          rm = fmaxf(rm, __shfl_xor(rm, 4));
          rm = fmaxf(rm, __shfl_xor(rm, 8));
          float mnew = fmaxf(mrow[s][j], rm);
          float corr = __expf(mrow[s][j] - mnew);
          mrow[s][j] = mnew;
          lpart[s][j] *= corr;
#pragma unroll
          for (int dt = 0; dt < 8; ++dt) o_acc[s][dt][j] *= corr;
        }
      }
#pragma unroll
      for (int j = 0; j < 4; ++j) {
        float p0 = __expf(sacc[0][j] - mrow[s][j]);
        float p1 = __expf(sacc[1][j] - mrow[s][j]);
        lpart[s][j] += p0 + p1;
        unsigned int u;
        asm("v_cvt_pk_bf16_f32 %0, %1, %2" : "=v"(u) : "v"(p0), "v"(p1));
        Pl[wave][(fq*4 + j)*40 + fr]      = (unsigned short)u;
        Pl[wave][(fq*4 + j)*40 + 16 + fr] = (unsigned short)(u >> 16);
      }
      asm volatile("s_waitcnt lgkmcnt(0)" ::: "memory");
      __builtin_amdgcn_sched_barrier(0);

      short8 pa = *reinterpret_cast<const short8*>(&Pl[wave][fr*40 + fq*8]);
#pragma unroll
      for (int dt = 0; dt < 8; ++dt) {
        const int row = dt * 16 + fr;
        short8 bv = *reinterpret_cast<const short8*>(
            kvb + 8192 + row * 64 + ((fq * 16) ^ ((((row ^ (row >> 2)) & 3)) << 4)));
        o_acc[s][dt] = __builtin_amdgcn_mfma_f32_16x16x32_bf16(pa, bv, o_acc[s][dt], 0, 0, 0);
      }
    }

    asm volatile("s_waitcnt vmcnt(0)" ::: "memory");
    __syncthreads();
    cur ^= 1;
  }

#pragma unroll
  for (int s = 0; s < 2; ++s)
#pragma unroll
    for (int j = 0; j < 4; ++j) {
      float l = lpart[s][j];
      l += __shfl_xor(l, 1);
      l += __shfl_xor(l, 2);
      l += __shfl_xor(l, 4);
      l += __shfl_xor(l, 8);
      float inv = 1.f / l;
      size_t r = (size_t)q0s[s] + fq*4 + j;
#pragma unroll
      for (int dt = 0; dt < 8; ++dt)
        Ob[r * QDIM + h * DH + dt*16 + fr] = f2bf(o_acc[s][dt][j] * inv);
    }
}

// ---------------- launch ----------------
extern "C" void kernel_launch(void* const* d_in, const int* in_sizes, int n_in,
                              void* d_out, int out_size, void* d_ws, size_t ws_size,
                              hipStream_t stream) {
  (void)in_sizes; (void)n_in; (void)out_size; (void)ws_size;
  const float* x    = (const float*)d_in[0];
  const float* Wq   = (const float*)d_in[1];
  const float* Wk   = (const float*)d_in[2];
  const float* Wv   = (const float*)d_in[3];
  const float* Wo   = (const float*)d_in[4];
  const float* cosb = (const float*)d_in[5];
  const float* sinb = (const float*)d_in[6];

  char* ws = (char*)d_ws;
  unsigned short* xb    = (unsigned short*)(ws);               // 16.8 MB (A of QKV; reused as Ab)
  unsigned short* Cqkv  = (unsigned short*)(ws + 100663296);   // 25.2 MB [Q|K|V] stride 6144
  unsigned short* VT    = (unsigned short*)(ws + 125829120);   // 4.2 MB
  unsigned short* Ab    = xb;                                  // attn output (xb dead after QKV)

  cvt_x<<<8192, 256, 0, stream>>>(x, xb);

  // QKV projection: 256x192 tiles -> 8m x 32n = 256 blocks; B = [Wq;Wk;Wv] f32, split 4096/5120
  gemm8p<2048, 6144, 4096, 256, 192, 1, 4, 4096, 5120>
      <<<256, 512, 0, stream>>>(xb, Wq, Wk, Wv, Cqkv);

  rope_fused<<<20480, 256, 0, stream>>>(Cqkv, cosb, sinb);
  transpose_v<<<dim3(32, 16), 256, 0, stream>>>(Cqkv + 5120, VT);

  attn_fwd<<<512, 256, 0, stream>>>(Cqkv, VT, Ab);

  // Output projection: 128x256 tiles -> 16m x 16n = 256 blocks; B = Wo f32
  gemm8p<2048, 4096, 4096, 128, 256, 0, 2, (1 << 30), (1 << 30)>
      <<<256, 512, 0, stream>>>(Ab, Wo, Wo, Wo, d_out);
}

// Round 10
// 305.971 us; speedup vs baseline: 1.1590x; 1.1590x over previous
//
#include <hip/hip_runtime.h>

#define S_LEN 2048
#define DMODEL 4096
#define NH 32
#define NKV 8
#define DH 128
#define QDIM (NH*DH)      // 4096
#define NQKV 6144         // fused projection width
#define SCALE 0.08838834764831845f

typedef __attribute__((ext_vector_type(8))) short short8;
typedef __attribute__((ext_vector_type(4))) float f32x4;
typedef __attribute__((ext_vector_type(4))) unsigned short us4;

__device__ __forceinline__ unsigned short f2bf(float f) {
  union { float f; unsigned int u; } v; v.f = f;
  unsigned int r = v.u + 0x7FFFu + ((v.u >> 16) & 1u);
  return (unsigned short)(r >> 16);
}
__device__ __forceinline__ float bf2f(unsigned short h) {
  union { unsigned int u; float f; } v; v.u = ((unsigned int)h) << 16;
  return v.f;
}

// ---------------- fused f32 -> bf16 convert for all 5 tensors ----------------
__global__ __launch_bounds__(256) void cvt_all(const float* __restrict__ x,
                                               const float* __restrict__ Wq,
                                               const float* __restrict__ Wk,
                                               const float* __restrict__ Wv,
                                               const float* __restrict__ Wo,
                                               unsigned short* __restrict__ xb,
                                               unsigned short* __restrict__ Wqkvb,
                                               unsigned short* __restrict__ Wob) {
  const int blk = blockIdx.x;
  const float* src; unsigned short* dst; int off;
  if (blk < 8192)       { src = x;  dst = xb;               off = blk; }
  else if (blk < 24576) { src = Wq; dst = Wqkvb;            off = blk - 8192; }
  else if (blk < 28672) { src = Wk; dst = Wqkvb + 16777216; off = blk - 24576; }
  else if (blk < 32768) { src = Wv; dst = Wqkvb + 20971520; off = blk - 28672; }
  else                  { src = Wo; dst = Wob;              off = blk - 32768; }
  int i = off * 256 + threadIdx.x;
  const float4 f = reinterpret_cast<const float4*>(src)[i];
  us4 o;
  o.x = f2bf(f.x); o.y = f2bf(f.y); o.z = f2bf(f.z); o.w = f2bf(f.w);
  reinterpret_cast<us4*>(dst)[i] = o;
}

// ---------------- (BM x BN) 8-phase GEMM, 2-buffer (round-8 proven) ----------------
template<int M_, int N_, int K_, int BM_, int BN_, int OUT_BF16, int CHN>
__global__ __launch_bounds__(512) void gemm8p(const unsigned short* __restrict__ A,
                                              const unsigned short* __restrict__ B,
                                              void* __restrict__ Cv) {
  constexpr int ATILE = BM_ * 128;
  constexpr int BTILE = BN_ * 128;
  constexpr int BUF = ATILE + BTILE;
  constexpr int LPA = BM_ / 64;
  constexpr int LPB = BN_ / 64;
  constexpr int VM  = LPA + LPB;
  constexpr int MI = BM_ / 32, NF = BN_ / 64;
  constexpr int MIL = MI / 2, NFL = NF / 2;
  constexpr int NT = K_ / 64;
  __shared__ char lds[2 * BUF];

  const int tid = threadIdx.x;
  const int lane = tid & 63, wave = tid >> 6;
  const int wm = wave >> 2, wn = wave & 3;
  const int fr = lane & 15, fq = lane >> 4;

  const int lin = blockIdx.x;
  const int xcd = lin & 7;
  const int slot = lin >> 3;
  const long n0 = (long)(xcd * CHN + slot % CHN) * BN_;
  const long m0 = (long)(slot / CHN) * BM_;

  auto STAGE_A = [&](int t, int c) {
#pragma unroll
    for (int u = 0; u < LPA; ++u) {
      int b = u * 8192 + tid * 16;
      int row = b >> 7;
      int off = (b & 127) ^ ((row & 7) << 4);
      __builtin_amdgcn_global_load_lds(
        (const __attribute__((address_space(1))) void*)((const char*)A + ((m0 + row) * (long)K_ + t * 64) * 2 + off),
        (__attribute__((address_space(3))) void*)(lds + c * BUF + b), 16, 0, 0);
    }
  };
  auto STAGE_B = [&](int t, int c) {
#pragma unroll
    for (int u = 0; u < LPB; ++u) {
      int b = u * 8192 + tid * 16;
      int row = b >> 7;
      int off = (b & 127) ^ ((row & 7) << 4);
      __builtin_amdgcn_global_load_lds(
        (const __attribute__((address_space(1))) void*)((const char*)B + ((n0 + row) * (long)K_ + t * 64) * 2 + off),
        (__attribute__((address_space(3))) void*)(lds + c * BUF + ATILE + b), 16, 0, 0);
    }
  };
#define VMCNT_STEADY() do { if constexpr (VM == 6) asm volatile("s_waitcnt vmcnt(6)" ::: "memory"); \
                            else if constexpr (VM == 7) asm volatile("s_waitcnt vmcnt(7)" ::: "memory"); \
                            else asm volatile("s_waitcnt vmcnt(8)" ::: "memory"); } while (0)

  f32x4 acc[MI][NF] = {};
  short8 af[MI][2];
  short8 bf[NF][2];

  STAGE_A(0, 0); STAGE_B(0, 0);
  STAGE_A(1, 1); STAGE_B(1, 1);
  VMCNT_STEADY();
  __builtin_amdgcn_s_barrier();

  for (int t = 0; t < NT; ++t) {
    const int c = t & 1;
    const char* tb = lds + c * BUF;

#pragma unroll
    for (int mi = 0; mi < MIL; ++mi) {
      int row = wm * (BM_ / 2) + mi * 16 + fr;
#pragma unroll
      for (int ks = 0; ks < 2; ++ks)
        af[mi][ks] = *(const short8*)(tb + row * 128 + ((ks * 64 + fq * 16) ^ ((row & 7) << 4)));
    }
#pragma unroll
    for (int ni = 0; ni < NFL; ++ni) {
      int row = wn * (BN_ / 4) + ni * 16 + fr;
#pragma unroll
      for (int ks = 0; ks < 2; ++ks)
        bf[ni][ks] = *(const short8*)(tb + ATILE + row * 128 + ((ks * 64 + fq * 16) ^ ((row & 7) << 4)));
    }
    __builtin_amdgcn_s_barrier();
    __builtin_amdgcn_s_setprio(1);
#pragma unroll
    for (int mi = 0; mi < MIL; ++mi)
#pragma unroll
      for (int ni = 0; ni < NFL; ++ni)
#pragma unroll
        for (int ks = 0; ks < 2; ++ks)
          acc[mi][ni] = __builtin_amdgcn_mfma_f32_16x16x32_bf16(af[mi][ks], bf[ni][ks], acc[mi][ni], 0, 0, 0);
    __builtin_amdgcn_s_setprio(0);
    __builtin_amdgcn_s_barrier();

#pragma unroll
    for (int mi = MIL; mi < MI; ++mi) {
      int row = wm * (BM_ / 2) + mi * 16 + fr;
#pragma unroll
      for (int ks = 0; ks < 2; ++ks)
        af[mi][ks] = *(const short8*)(tb + row * 128 + ((ks * 64 + fq * 16) ^ ((row & 7) << 4)));
    }
#pragma unroll
    for (int ni = NFL; ni < NF; ++ni) {
      int row = wn * (BN_ / 4) + ni * 16 + fr;
#pragma unroll
      for (int ks = 0; ks < 2; ++ks)
        bf[ni][ks] = *(const short8*)(tb + ATILE + row * 128 + ((ks * 64 + fq * 16) ^ ((row & 7) << 4)));
    }
    __builtin_amdgcn_s_barrier();
    __builtin_amdgcn_s_setprio(1);
#pragma unroll
    for (int mi = 0; mi < MIL; ++mi)
#pragma unroll
      for (int ni = NFL; ni < NF; ++ni)
#pragma unroll
        for (int ks = 0; ks < 2; ++ks)
          acc[mi][ni] = __builtin_amdgcn_mfma_f32_16x16x32_bf16(af[mi][ks], bf[ni][ks], acc[mi][ni], 0, 0, 0);
    __builtin_amdgcn_s_setprio(0);
    __builtin_amdgcn_s_barrier();

    if (t + 2 < NT) STAGE_A(t + 2, c);
    __builtin_amdgcn_s_setprio(1);
#pragma unroll
    for (int mi = MIL; mi < MI; ++mi)
#pragma unroll
      for (int ni = 0; ni < NFL; ++ni)
#pragma unroll
        for (int ks = 0; ks < 2; ++ks)
          acc[mi][ni] = __builtin_amdgcn_mfma_f32_16x16x32_bf16(af[mi][ks], bf[ni][ks], acc[mi][ni], 0, 0, 0);
    __builtin_amdgcn_s_setprio(0);
    __builtin_amdgcn_s_barrier();

    if (t + 2 < NT) STAGE_B(t + 2, c);
    __builtin_amdgcn_s_setprio(1);
#pragma unroll
    for (int mi = MIL; mi < MI; ++mi)
#pragma unroll
      for (int ni = NFL; ni < NF; ++ni)
#pragma unroll
        for (int ks = 0; ks < 2; ++ks)
          acc[mi][ni] = __builtin_amdgcn_mfma_f32_16x16x32_bf16(af[mi][ks], bf[ni][ks], acc[mi][ni], 0, 0, 0);
    __builtin_amdgcn_s_setprio(0);
    if (t + 2 < NT) { VMCNT_STEADY(); }
    else if (t + 1 < NT) { asm volatile("s_waitcnt vmcnt(0)" ::: "memory"); }
    __builtin_amdgcn_s_barrier();
  }
#undef VMCNT_STEADY

#pragma unroll
  for (int mi = 0; mi < MI; ++mi)
#pragma unroll
    for (int ni = 0; ni < NF; ++ni)
#pragma unroll
      for (int j = 0; j < 4; ++j) {
        long r = m0 + wm * (BM_ / 2) + mi * 16 + fq * 4 + j;
        long cc = n0 + wn * (BN_ / 4) + ni * 16 + fr;
        float v = acc[mi][ni][j];
        if (OUT_BF16) ((unsigned short*)Cv)[r * N_ + cc] = f2bf(v);
        else          ((float*)Cv)[r * N_ + cc] = v;
      }
}

// ---------------- (BM x BN) 8-phase GEMM, 3-buffer spread-stage variant ----------------
// Staging for t+2 goes to buf (t+2)%3 (never the buffer being read), so stage-issue can
// overlap ds_read+MFMA in ph1-ph3; counted vmcnt(6) at ph4 only. Tail drains vmcnt(0).
template<int M_, int N_, int K_, int BM_, int BN_, int OUT_BF16, int CHN>
__global__ __launch_bounds__(512) void gemm8p3(const unsigned short* __restrict__ A,
                                               const unsigned short* __restrict__ B,
                                               void* __restrict__ Cv) {
  constexpr int ATILE = BM_ * 128;
  constexpr int BTILE = BN_ * 128;
  constexpr int BUF = ATILE + BTILE;       // 48 KB for 128x256
  constexpr int LPA = BM_ / 64;            // 2
  constexpr int LPB = BN_ / 64;            // 4
  constexpr int VM  = LPA + LPB;           // 6
  constexpr int MI = BM_ / 32, NF = BN_ / 64;
  constexpr int MIL = MI / 2, NFL = NF / 2;
  constexpr int NT = K_ / 64;
  __shared__ char lds[3 * BUF];            // 144 KB

  const int tid = threadIdx.x;
  const int lane = tid & 63, wave = tid >> 6;
  const int wm = wave >> 2, wn = wave & 3;
  const int fr = lane & 15, fq = lane >> 4;

  const int lin = blockIdx.x;
  const int xcd = lin & 7;
  const int slot = lin >> 3;
  const long n0 = (long)(xcd * CHN + slot % CHN) * BN_;
  const long m0 = (long)(slot / CHN) * BM_;

  auto STAGE_A = [&](int t, int c) {
#pragma unroll
    for (int u = 0; u < LPA; ++u) {
      int b = u * 8192 + tid * 16;
      int row = b >> 7;
      int off = (b & 127) ^ ((row & 7) << 4);
      __builtin_amdgcn_global_load_lds(
        (const __attribute__((address_space(1))) void*)((const char*)A + ((m0 + row) * (long)K_ + t * 64) * 2 + off),
        (__attribute__((address_space(3))) void*)(lds + c * BUF + b), 16, 0, 0);
    }
  };
  auto STAGE_B_HALF = [&](int t, int c, int half) {
#pragma unroll
    for (int u = 0; u < LPB / 2; ++u) {
      int b = (half * (LPB / 2) + u) * 8192 + tid * 16;
      int row = b >> 7;
      int off = (b & 127) ^ ((row & 7) << 4);
      __builtin_amdgcn_global_load_lds(
        (const __attribute__((address_space(1))) void*)((const char*)B + ((n0 + row) * (long)K_ + t * 64) * 2 + off),
        (__attribute__((address_space(3))) void*)(lds + c * BUF + ATILE + b), 16, 0, 0);
    }
  };

  f32x4 acc[MI][NF] = {};
  short8 af[MI][2];
  short8 bf[NF][2];

  // prologue: tiles 0,1 fully staged, drained
  STAGE_A(0, 0); STAGE_B_HALF(0, 0, 0); STAGE_B_HALF(0, 0, 1);
  STAGE_A(1, 1); STAGE_B_HALF(1, 1, 0); STAGE_B_HALF(1, 1, 1);
  asm volatile("s_waitcnt vmcnt(0)" ::: "memory");
  __builtin_amdgcn_s_barrier();

  for (int t = 0; t < NT; ++t) {
    const char* tb = lds + (t % 3) * BUF;
    const int c2 = (t + 2) % 3;

    // ---- ph1: af-lo + bf-lo reads; stage A(t+2); MFMA lo x lo ----
#pragma unroll
    for (int mi = 0; mi < MIL; ++mi) {
      int row = wm * (BM_ / 2) + mi * 16 + fr;
#pragma unroll
      for (int ks = 0; ks < 2; ++ks)
        af[mi][ks] = *(const short8*)(tb + row * 128 + ((ks * 64 + fq * 16) ^ ((row & 7) << 4)));
    }
#pragma unroll
    for (int ni = 0; ni < NFL; ++ni) {
      int row = wn * (BN_ / 4) + ni * 16 + fr;
#pragma unroll
      for (int ks = 0; ks < 2; ++ks)
        bf[ni][ks] = *(const short8*)(tb + ATILE + row * 128 + ((ks * 64 + fq * 16) ^ ((row & 7) << 4)));
    }
    if (t + 2 < NT) STAGE_A(t + 2, c2);
    __builtin_amdgcn_s_barrier();
    __builtin_amdgcn_s_setprio(1);
#pragma unroll
    for (int mi = 0; mi < MIL; ++mi)
#pragma unroll
      for (int ni = 0; ni < NFL; ++ni)
#pragma unroll
        for (int ks = 0; ks < 2; ++ks)
          acc[mi][ni] = __builtin_amdgcn_mfma_f32_16x16x32_bf16(af[mi][ks], bf[ni][ks], acc[mi][ni], 0, 0, 0);
    __builtin_amdgcn_s_setprio(0);
    __builtin_amdgcn_s_barrier();

    // ---- ph2: af-hi + bf-hi reads; stage B(t+2) half 0; MFMA lo x hi ----
#pragma unroll
    for (int mi = MIL; mi < MI; ++mi) {
      int row = wm * (BM_ / 2) + mi * 16 + fr;
#pragma unroll
      for (int ks = 0; ks < 2; ++ks)
        af[mi][ks] = *(const short8*)(tb + row * 128 + ((ks * 64 + fq * 16) ^ ((row & 7) << 4)));
    }
#pragma unroll
    for (int ni = NFL; ni < NF; ++ni) {
      int row = wn * (BN_ / 4) + ni * 16 + fr;
#pragma unroll
      for (int ks = 0; ks < 2; ++ks)
        bf[ni][ks] = *(const short8*)(tb + ATILE + row * 128 + ((ks * 64 + fq * 16) ^ ((row & 7) << 4)));
    }
    if (t + 2 < NT) STAGE_B_HALF(t + 2, c2, 0);
    __builtin_amdgcn_s_barrier();
    __builtin_amdgcn_s_setprio(1);
#pragma unroll
    for (int mi = 0; mi < MIL; ++mi)
#pragma unroll
      for (int ni = NFL; ni < NF; ++ni)
#pragma unroll
        for (int ks = 0; ks < 2; ++ks)
          acc[mi][ni] = __builtin_amdgcn_mfma_f32_16x16x32_bf16(af[mi][ks], bf[ni][ks], acc[mi][ni], 0, 0, 0);
    __builtin_amdgcn_s_setprio(0);
    __builtin_amdgcn_s_barrier();

    // ---- ph3: stage B(t+2) half 1; MFMA hi x lo ----
    if (t + 2 < NT) STAGE_B_HALF(t + 2, c2, 1);
    __builtin_amdgcn_s_setprio(1);
#pragma unroll
    for (int mi = MIL; mi < MI; ++mi)
#pragma unroll
      for (int ni = 0; ni < NFL; ++ni)
#pragma unroll
        for (int ks = 0; ks < 2; ++ks)
          acc[mi][ni] = __builtin_amdgcn_mfma_f32_16x16x32_bf16(af[mi][ks], bf[ni][ks], acc[mi][ni], 0, 0, 0);
    __builtin_amdgcn_s_setprio(0);
    __builtin_amdgcn_s_barrier();

    // ---- ph4: MFMA hi x hi; counted vmcnt; barrier ----
    __builtin_amdgcn_s_setprio(1);
#pragma unroll
    for (int mi = MIL; mi < MI; ++mi)
#pragma unroll
      for (int ni = NFL; ni < NF; ++ni)
#pragma unroll
        for (int ks = 0; ks < 2; ++ks)
          acc[mi][ni] = __builtin_amdgcn_mfma_f32_16x16x32_bf16(af[mi][ks], bf[ni][ks], acc[mi][ni], 0, 0, 0);
    __builtin_amdgcn_s_setprio(0);
    if (t + 2 < NT) { asm volatile("s_waitcnt vmcnt(6)" ::: "memory"); }
    else if (t + 1 < NT) { asm volatile("s_waitcnt vmcnt(0)" ::: "memory"); }
    __builtin_amdgcn_s_barrier();
  }
  (void)VM;

#pragma unroll
  for (int mi = 0; mi < MI; ++mi)
#pragma unroll
    for (int ni = 0; ni < NF; ++ni)
#pragma unroll
      for (int j = 0; j < 4; ++j) {
        long r = m0 + wm * (BM_ / 2) + mi * 16 + fq * 4 + j;
        long cc = n0 + wn * (BN_ / 4) + ni * 16 + fr;
        float v = acc[mi][ni][j];
        if (OUT_BF16) ((unsigned short*)Cv)[r * N_ + cc] = f2bf(v);
        else          ((float*)Cv)[r * N_ + cc] = v;
      }
}

// ---------------- YaRN RoPE in-place on fused QKV buffer (stride 6144) ----------------
__global__ __launch_bounds__(256) void rope_fused(unsigned short* __restrict__ C,
                                                  const float* __restrict__ cosb,
                                                  const float* __restrict__ sinb) {
  int idx = blockIdx.x * 256 + threadIdx.x;
  int i = idx & 63;
  int t = idx >> 6;       // s*40 + hh
  int hh = t % 40;
  int s = t / 40;
  const bool isQ = hh < 32;
  unsigned short* row = C + (size_t)s * NQKV + (isQ ? hh * DH : 4096 + (hh - 32) * DH);
  float sc = isQ ? SCALE : 1.0f;
  float c  = cosb[s * DH + i];
  float sn = sinb[s * DH + i];
  float x1 = bf2f(row[i]);
  float x2 = bf2f(row[i + 64]);
  row[i]      = f2bf((x1 * c - x2 * sn) * sc);
  row[i + 64] = f2bf((x2 * c + x1 * sn) * sc);
}

// ---------------- V transpose: C[s][5120+e] -> VT[kvh][d][s] ----------------
__global__ __launch_bounds__(256) void transpose_v(const unsigned short* __restrict__ Vbuf,
                                                   unsigned short* __restrict__ VT) {
  __shared__ unsigned short t[64][72];
  const int s0 = blockIdx.x * 64, e0 = blockIdx.y * 64;
  const int r = threadIdx.x >> 3, c = (threadIdx.x & 7) * 8;
#pragma unroll
  for (int half = 0; half < 2; ++half) {
    int row = r + half * 32;
    *reinterpret_cast<short8*>(&t[row][c]) =
        *reinterpret_cast<const short8*>(Vbuf + (size_t)(s0 + row) * NQKV + e0 + c);
  }
  __syncthreads();
  const int hh = e0 >> 7, dbase = e0 & 127;
#pragma unroll
  for (int half = 0; half < 2; ++half) {
    int row = r + half * 32;
    short8 o;
#pragma unroll
    for (int j = 0; j < 8; ++j) ((unsigned short*)&o)[j] = t[c + j][row];
    *reinterpret_cast<short8*>(VT + (size_t)hh * (DH * (size_t)S_LEN)
                               + (size_t)(dbase + row) * S_LEN + s0 + c) = o;
  }
}

// ---------------- GQA causal flash attention (round-6, unchanged) ----------------
__global__ __launch_bounds__(256) void attn_fwd(const unsigned short* __restrict__ C,
                                                const unsigned short* __restrict__ VT,
                                                unsigned short* __restrict__ Ob) {
  __shared__ unsigned short KVs[2][8192];   // 16 KB per buffer: K[32][128] swz @0, V^T[128][32] swz @8KB
  __shared__ unsigned short Pl[4][16 * 40];
  const int tid = threadIdx.x, lane = tid & 63, wave = tid >> 6;
  const int kvh = blockIdx.x & 7;
  const int p = blockIdx.x >> 3;
  const int h = kvh * 4 + wave;
  const int fr = lane & 15, fq = lane >> 4;
  const int q0s[2] = { p * 16, (127 - p) * 16 };
  const int tilesA = (p * 16 + 47) >> 5;
  const int tilesB = ((127 - p) * 16 + 47) >> 5;

  const unsigned short* Qbase = C + (size_t)h * DH;
  const unsigned short* Kbase = C + 4096 + (size_t)kvh * DH;
  const unsigned short* Vbase = VT + (size_t)kvh * (DH * (size_t)S_LEN);

  short8 qf[2][4];
#pragma unroll
  for (int s = 0; s < 2; ++s)
#pragma unroll
    for (int dc = 0; dc < 4; ++dc)
      qf[s][dc] = *reinterpret_cast<const short8*>(
          Qbase + (size_t)(q0s[s] + fr) * NQKV + dc * 32 + fq * 8);

  f32x4 o_acc[2][8] = {};
  float mrow[2][4] = {{-1e30f,-1e30f,-1e30f,-1e30f},{-1e30f,-1e30f,-1e30f,-1e30f}};
  float lpart[2][4] = {};

  auto STAGE = [&](int t, int buf) {
    const int kv0 = t * 32;
    char* dst = (char*)&KVs[buf][0];
#pragma unroll
    for (int sh = 0; sh < 2; ++sh) {
      int b = sh * 4096 + tid * 16;
      int krow = b >> 8;
      int kcol = (b & 255) ^ ((krow & 7) << 4);
      __builtin_amdgcn_global_load_lds(
          (const __attribute__((address_space(1))) void*)(Kbase + (size_t)(kv0 + krow) * NQKV + (kcol >> 1)),
          (__attribute__((address_space(3))) void*)(dst + b), 16, 0, 0);
      int vrow = b >> 6;
      int vcol = (b & 63) ^ ((((vrow ^ (vrow >> 2)) & 3)) << 4);
      __builtin_amdgcn_global_load_lds(
          (const __attribute__((address_space(1))) void*)(Vbase + (size_t)vrow * S_LEN + kv0 + (vcol >> 1)),
          (__attribute__((address_space(3))) void*)(dst + 8192 + b), 16, 0, 0);
    }
  };

  int cur = 0;
  STAGE(0, 0);
  asm volatile("s_waitcnt vmcnt(0)" ::: "memory");
  __syncthreads();

  for (int t = 0; t < tilesB; ++t) {
    const int kv0 = t * 32;
    if (t + 1 < tilesB) STAGE(t + 1, cur ^ 1);
    const char* kvb = (const char*)&KVs[cur][0];

#pragma unroll
    for (int s = 0; s < 2; ++s) {
      if (s == 0 && t >= tilesA) continue;
      const int q0 = q0s[s];

      f32x4 sacc[2] = {};
#pragma unroll
      for (int nt = 0; nt < 2; ++nt) {
        const int row = nt * 16 + fr;
#pragma unroll
        for (int dc = 0; dc < 4; ++dc) {
          short8 kf = *reinterpret_cast<const short8*>(
              kvb + row * 256 + ((dc * 64 + fq * 16) ^ ((row & 7) << 4)));
          sacc[nt] = __builtin_amdgcn_mfma_f32_16x16x32_bf16(qf[s][dc], kf, sacc[nt], 0, 0, 0);
        }
      }

      const bool needMask = (kv0 + 32 > q0);
      if (needMask) {
#pragma unroll
        for (int j = 0; j < 4; ++j) {
          int qrow = q0 + fq * 4 + j;
#pragma unroll
          for (int nt = 0; nt < 2; ++nt)
            sacc[nt][j] = ((kv0 + nt*16 + fr) <= qrow) ? sacc[nt][j] : -1e30f;
        }
      }
      bool ok = true;
      float lm[4];
#pragma unroll
      for (int j = 0; j < 4; ++j) {
        lm[j] = fmaxf(sacc[0][j], sacc[1][j]);
        ok = ok && (lm[j] <= mrow[s][j] + 8.f);
      }
      if (!__all(ok)) {
#pragma unroll
        for (int j = 0; j < 4; ++j) {
          float rm = lm[j];
          rm = fmaxf(rm, __shfl_xor(rm, 1));
          rm = fmaxf(rm, __shfl_xor(rm, 2));
          rm = fmaxf(rm, __shfl_xor(rm, 4));
          rm = fmaxf(rm, __shfl_xor(rm, 8));
          float mnew = fmaxf(mrow[s][j], rm);
          float corr = __expf(mrow[s][j] - mnew);
          mrow[s][j] = mnew;
          lpart[s][j] *= corr;
#pragma unroll
          for (int dt = 0; dt < 8; ++dt) o_acc[s][dt][j] *= corr;
        }
      }
#pragma unroll
      for (int j = 0; j < 4; ++j) {
        float p0 = __expf(sacc[0][j] - mrow[s][j]);
        float p1 = __expf(sacc[1][j] - mrow[s][j]);
        lpart[s][j] += p0 + p1;
        unsigned int u;
        asm("v_cvt_pk_bf16_f32 %0, %1, %2" : "=v"(u) : "v"(p0), "v"(p1));
        Pl[wave][(fq*4 + j)*40 + fr]      = (unsigned short)u;
        Pl[wave][(fq*4 + j)*40 + 16 + fr] = (unsigned short)(u >> 16);
      }
      asm volatile("s_waitcnt lgkmcnt(0)" ::: "memory");
      __builtin_amdgcn_sched_barrier(0);

      short8 pa = *reinterpret_cast<const short8*>(&Pl[wave][fr*40 + fq*8]);
#pragma unroll
      for (int dt = 0; dt < 8; ++dt) {
        const int row = dt * 16 + fr;
        short8 bv = *reinterpret_cast<const short8*>(
            kvb + 8192 + row * 64 + ((fq * 16) ^ ((((row ^ (row >> 2)) & 3)) << 4)));
        o_acc[s][dt] = __builtin_amdgcn_mfma_f32_16x16x32_bf16(pa, bv, o_acc[s][dt], 0, 0, 0);
      }
    }

    asm volatile("s_waitcnt vmcnt(0)" ::: "memory");
    __syncthreads();
    cur ^= 1;
  }

#pragma unroll
  for (int s = 0; s < 2; ++s)
#pragma unroll
    for (int j = 0; j < 4; ++j) {
      float l = lpart[s][j];
      l += __shfl_xor(l, 1);
      l += __shfl_xor(l, 2);
      l += __shfl_xor(l, 4);
      l += __shfl_xor(l, 8);
      float inv = 1.f / l;
      size_t r = (size_t)q0s[s] + fq*4 + j;
#pragma unroll
      for (int dt = 0; dt < 8; ++dt)
        Ob[r * QDIM + h * DH + dt*16 + fr] = f2bf(o_acc[s][dt][j] * inv);
    }
}

// ---------------- launch ----------------
extern "C" void kernel_launch(void* const* d_in, const int* in_sizes, int n_in,
                              void* d_out, int out_size, void* d_ws, size_t ws_size,
                              hipStream_t stream) {
  (void)in_sizes; (void)n_in; (void)out_size; (void)ws_size;
  const float* x    = (const float*)d_in[0];
  const float* Wq   = (const float*)d_in[1];
  const float* Wk   = (const float*)d_in[2];
  const float* Wv   = (const float*)d_in[3];
  const float* Wo   = (const float*)d_in[4];
  const float* cosb = (const float*)d_in[5];
  const float* sinb = (const float*)d_in[6];

  char* ws = (char*)d_ws;
  unsigned short* xb    = (unsigned short*)(ws);               // 16.8 MB (dead after QKV gemm)
  unsigned short* Wqkvb = (unsigned short*)(ws + 16777216);    // 50.3 MB [Wq;Wk;Wv]
  unsigned short* Wob   = (unsigned short*)(ws + 67108864);    // 33.6 MB
  unsigned short* Cqkv  = (unsigned short*)(ws + 100663296);   // 25.2 MB [Q|K|V] stride 6144
  unsigned short* VT    = (unsigned short*)(ws + 125829120);   // 4.2 MB
  unsigned short* Ab    = xb;                                  // reuse

  cvt_all<<<49152, 256, 0, stream>>>(x, Wq, Wk, Wv, Wo, xb, Wqkvb, Wob);

  // QKV projection: round-8 proven 2-buffer schedule. 256x192 tiles -> 256 blocks.
  gemm8p<2048, 6144, 4096, 256, 192, 1, 4><<<256, 512, 0, stream>>>(xb, Wqkvb, Cqkv);

  rope_fused<<<20480, 256, 0, stream>>>(Cqkv, cosb, sinb);
  transpose_v<<<dim3(32, 16), 256, 0, stream>>>(Cqkv + 5120, VT);

  attn_fwd<<<512, 256, 0, stream>>>(Cqkv, VT, Ab);

  // Output projection: 3-buffer spread-stage schedule. 128x256 tiles -> 256 blocks.
  gemm8p3<2048, 4096, 4096, 128, 256, 0, 2><<<256, 512, 0, stream>>>(Ab, Wob, d_out);
}